// Round 1
// baseline (1048.536 us; speedup 1.0000x reference)
//
#include <hip/hip_runtime.h>
#include <hip/hip_fp16.h>
#include <stdint.h>

typedef float  f32x4  __attribute__((ext_vector_type(4)));
typedef short  bf16x8 __attribute__((ext_vector_type(8)));
typedef _Float16 h2v  __attribute__((ext_vector_type(2)));

#define NEGV -10000.0f

__device__ __forceinline__ unsigned short f32_to_bf16(float f){
  union { float f; uint32_t u; } v; v.f = f;
  uint32_t u = v.u;
  u += 0x7fffu + ((u >> 16) & 1u);          // RNE
  return (unsigned short)(u >> 16);
}
__device__ __forceinline__ float bf16_lo(uint32_t u){
  union { uint32_t u; float f; } v; v.u = (u & 0xffffu) << 16; return v.f;
}
__device__ __forceinline__ float bf16_hi(uint32_t u){
  union { uint32_t u; float f; } v; v.u = u & 0xffff0000u; return v.f;
}
__device__ __forceinline__ float fsig(float x){ return 1.0f / (1.0f + __expf(-x)); }
__device__ __forceinline__ float ftanh_(float x){
  x = fminf(15.0f, fmaxf(-15.0f, x));
  const float e = __expf(2.0f * x);
  return (e - 1.0f) / (e + 1.0f);
}
// e5m2 ("bf8") = f16 rounded to its top byte
__device__ __forceinline__ uint32_t enc_bf8(float x){
  const unsigned short h = __half_as_ushort(__float2half(x));
  return (uint32_t)((h + 0x80u) >> 8) & 0xffu;
}
__device__ __forceinline__ float fdot2f(uint32_t w, uint32_t h, float acc){
#if __has_builtin(__builtin_amdgcn_fdot2)
  union { uint32_t u; h2v h; } a, b;
  a.u = w; b.u = h;
  return __builtin_amdgcn_fdot2(a.h, b.h, acc, false);
#else
  acc += __half2float(__ushort_as_half((unsigned short)(w & 0xffffu))) *
         __half2float(__ushort_as_half((unsigned short)(h & 0xffffu)));
  acc += __half2float(__ushort_as_half((unsigned short)(w >> 16))) *
         __half2float(__ushort_as_half((unsigned short)(h >> 16)));
  return acc;
#endif
}

// ---------------------------------------------------------------------------
// Quantize Whh_{f,b} [1024,256] f32 -> bf8(e5m2), rows gate-interleaved:
// out row n' = 4*u + g  <-  src row g*256 + u.  Layout: [dir][n'][64 dwords].
// ---------------------------------------------------------------------------
__global__ __launch_bounds__(256) void k_quant(
    const float* __restrict__ whh_f, const float* __restrict__ whh_b,
    uint32_t* __restrict__ wq)
{
  const int id  = blockIdx.x * 256 + threadIdx.x;   // 0..131071
  const int dir = id >> 16;
  const int rem = id & 0xffff;
  const int np  = rem >> 6;
  const int d   = rem & 63;
  const int u = np >> 2, g = np & 3;
  const float* __restrict__ w = dir ? whh_b : whh_f;
  const float4 v = *(const float4*)(w + (size_t)(g * 256 + u) * 256 + d * 4);
  wq[id] = enc_bf8(v.x) | (enc_bf8(v.y) << 8) | (enc_bf8(v.z) << 16) | (enc_bf8(v.w) << 24);
}

// ---------------------------------------------------------------------------
// XP[m][n'] = embed[sent[m]] @ Wih' ^T + b'   (bf16 MFMA, 128x128 tiles)
// m = b*256+t (16384), n' = dir*1024 + gate-interleaved col (2048), K=256.
// ---------------------------------------------------------------------------
__global__ __launch_bounds__(256) void k_xproj(
    const int* __restrict__ sent, const float* __restrict__ embed,
    const float* __restrict__ wih_f, const float* __restrict__ wih_b,
    const float* __restrict__ bias_f, const float* __restrict__ bias_b,
    unsigned short* __restrict__ xp)
{
  __shared__ __align__(16) short At[128 * 32];
  __shared__ __align__(16) short Bt[128 * 32];
  const int bid = blockIdx.x;
  const int tm = bid & 127;
  const int tn = bid >> 7;                  // 0..15
  const int dir = tn >> 3;
  const int nloc0 = (tn & 7) * 128;
  const float* __restrict__ wsrc = dir ? wih_b : wih_f;
  const float* __restrict__ bsrc = dir ? bias_b : bias_f;

  const int tid = threadIdx.x;
  const int wv = tid >> 6;
  const int lane = tid & 63;
  const int lr = lane & 15;
  const int lq = lane >> 4;

  const int r  = tid >> 1;
  const int ch = (tid & 1) * 16;

  const int tok = sent[tm * 128 + r];
  const int nprow = nloc0 + r;
  const float* arow = embed + (size_t)tok * 256 + ch;
  const float* brow = wsrc + (size_t)((nprow & 3) * 256 + (nprow >> 2)) * 256 + ch;
  short* at_dst = At + r * 32 + ch;
  short* bt_dst = Bt + r * 32 + ch;

  f32x4 acc[2][8];
  #pragma unroll
  for (int i = 0; i < 2; i++)
    #pragma unroll
    for (int n = 0; n < 8; n++)
      acc[i][n] = (f32x4){0.f, 0.f, 0.f, 0.f};

  for (int k0 = 0; k0 < 256; k0 += 32) {
    #pragma unroll
    for (int qq = 0; qq < 4; qq++) {
      const float4 va = *(const float4*)(arow + k0 + qq * 4);
      const float4 vb = *(const float4*)(brow + k0 + qq * 4);
      short4 sa, sb;
      sa.x = (short)f32_to_bf16(va.x); sa.y = (short)f32_to_bf16(va.y);
      sa.z = (short)f32_to_bf16(va.z); sa.w = (short)f32_to_bf16(va.w);
      sb.x = (short)f32_to_bf16(vb.x); sb.y = (short)f32_to_bf16(vb.y);
      sb.z = (short)f32_to_bf16(vb.z); sb.w = (short)f32_to_bf16(vb.w);
      *(short4*)(at_dst + qq * 4) = sa;
      *(short4*)(bt_dst + qq * 4) = sb;
    }
    __syncthreads();
    bf16x8 bfr[8];
    #pragma unroll
    for (int n = 0; n < 8; n++)
      bfr[n] = *(const bf16x8*)(Bt + (n * 16 + lr) * 32 + lq * 8);
    #pragma unroll
    for (int i = 0; i < 2; i++) {
      const bf16x8 af = *(const bf16x8*)(At + (wv * 32 + i * 16 + lr) * 32 + lq * 8);
      #pragma unroll
      for (int n = 0; n < 8; n++)
        acc[i][n] = __builtin_amdgcn_mfma_f32_16x16x32_bf16(af, bfr[n], acc[i][n], 0, 0, 0);
    }
    __syncthreads();
  }
  #pragma unroll
  for (int i = 0; i < 2; i++) {
    #pragma unroll
    for (int n = 0; n < 8; n++) {
      const int nloc = nloc0 + n * 16 + lr;
      const float bias = bsrc[(nloc & 3) * 256 + (nloc >> 2)];
      #pragma unroll
      for (int rr = 0; rr < 4; rr++) {
        const int m = tm * 128 + wv * 32 + i * 16 + lq * 4 + rr;
        xp[(size_t)m * 2048 + dir * 1024 + nloc] = f32_to_bf16(acc[i][n][rr] + bias);
      }
    }
  }
}

// ---------------------------------------------------------------------------
// Persistent LSTM: 1 WG (512 thr, 8 waves) per (b,dir). Whh bf8 in VGPRs
// as MFMA A-fragments; per step z = mfma(Whh, replicate(h)) + xp.
// Gate-interleaved rows => lane's f32x4 acc = (i,f,g,o) of one unit.
// ---------------------------------------------------------------------------
__global__ __launch_bounds__(512) void k_lstm(
    const unsigned short* __restrict__ xp, const uint32_t* __restrict__ wq,
    __half* __restrict__ hout)
{
  __shared__ __align__(8) unsigned char hbuf8[256];
  __shared__ __align__(16) float zs[1024];
  const int bid = blockIdx.x;
  const int dir = bid & 1;
  const int b = bid >> 1;
  const int tid = threadIdx.x;
  const int w = tid >> 6;          // wave 0..7
  const int l = tid & 63;
  const int lr = l & 15;           // col within tile
  const int q = l >> 4;            // quad -> k-offset q*8

  long afr[8][8];
  {
    const uint32_t* wb = wq + dir * 65536;
    #pragma unroll
    for (int ni = 0; ni < 8; ni++) {
      const uint32_t* rp = wb + (w * 128 + ni * 16 + lr) * 64 + q * 2;
      #pragma unroll
      for (int kt = 0; kt < 8; kt++) {
        const uint2 ww = *(const uint2*)(rp + kt * 8);
        afr[ni][kt] = (long)(((unsigned long long)ww.y << 32) | (unsigned long long)ww.x);
      }
    }
  }
  float c = 0.0f;
  if (tid < 256) hbuf8[tid] = 0;
  const unsigned short* xpb = xp + (size_t)b * (256 * 2048) + dir * 1024 + w * 128 + q * 4;
  __half* hb = hout + (size_t)b * (256 * 512) + dir * 256 + tid;   // tid<256 uses this
  __syncthreads();

  for (int s = 0; s < 256; s++) {
    const int t = dir ? (255 - s) : s;
    long bfr[8];
    #pragma unroll
    for (int kt = 0; kt < 8; kt++)
      bfr[kt] = *(const long*)(hbuf8 + kt * 32 + q * 8);
    f32x4 acc[8];
    {
      const unsigned short* xr = xpb + (size_t)t * 2048;
      #pragma unroll
      for (int ni = 0; ni < 8; ni++) {
        const uint2 xv = *(const uint2*)(xr + ni * 16);
        acc[ni].x = bf16_lo(xv.x);
        acc[ni].y = bf16_hi(xv.x);
        acc[ni].z = bf16_lo(xv.y);
        acc[ni].w = bf16_hi(xv.y);
      }
    }
    #pragma unroll
    for (int kt = 0; kt < 8; kt++)
      #pragma unroll
      for (int ni = 0; ni < 8; ni++)
        acc[ni] = __builtin_amdgcn_mfma_f32_16x16x32_bf8_bf8(afr[ni][kt], bfr[kt], acc[ni], 0, 0, 0);
    if (lr == 0) {
      #pragma unroll
      for (int ni = 0; ni < 8; ni++)
        *(f32x4*)(zs + (w * 32 + ni * 4 + q) * 4) = acc[ni];
    }
    __syncthreads();
    if (tid < 256) {
      const float4 z4 = *(const float4*)(zs + tid * 4);
      const float ig = fsig(z4.x);
      const float fg = fsig(z4.y);
      const float gg = ftanh_(z4.z);
      const float og = fsig(z4.w);
      c = fg * c + ig * gg;
      const float h = og * ftanh_(c);
      hb[(size_t)t * 512] = __float2half(h);
      const unsigned short h16 = __half_as_ushort(__float2half(h));
      hbuf8[tid] = (unsigned char)((h16 + 0x80u) >> 8);
    }
    __syncthreads();
  }
}

// ---------------------------------------------------------------------------
// feats[b][t][n] = H[b][t][:512] . Wout[n] + bout[n]   (f16 dot2, Wout in LDS)
// ---------------------------------------------------------------------------
__global__ __launch_bounds__(256) void k_feats(
    const __half* __restrict__ hg, const float* __restrict__ wout,
    const float* __restrict__ bout, float* __restrict__ feats)
{
  __shared__ uint32_t W2[32 * 257];
  __shared__ float bo[32];
  const int b = blockIdx.x;
  const int tid = threadIdx.x;
  #pragma unroll
  for (int i = 0; i < 32; i++) {
    const float2 v = *(const float2*)(wout + (size_t)i * 512 + tid * 2);
    const uint32_t lo = (uint32_t)__half_as_ushort(__float2half(v.x));
    const uint32_t hi = (uint32_t)__half_as_ushort(__float2half(v.y));
    W2[i * 257 + tid] = lo | (hi << 16);
  }
  if (tid < 32) bo[tid] = bout[tid];
  __syncthreads();
  const int n = tid & 31;
  const int tg = tid >> 5;
  const uint32_t* hrow0 = (const uint32_t*)(hg + (size_t)b * (256 * 512));
  for (int tt = 0; tt < 32; tt++) {
    const int t = tg * 32 + tt;
    const uint4* hr = (const uint4*)(hrow0 + t * 256);
    float a0 = 0.f, a1 = 0.f, a2 = 0.f, a3 = 0.f;
    #pragma unroll
    for (int qd = 0; qd < 64; qd++) {
      const uint4 hq = hr[qd];
      a0 = fdot2f(W2[n * 257 + qd * 4 + 0], hq.x, a0);
      a1 = fdot2f(W2[n * 257 + qd * 4 + 1], hq.y, a1);
      a2 = fdot2f(W2[n * 257 + qd * 4 + 2], hq.z, a2);
      a3 = fdot2f(W2[n * 257 + qd * 4 + 3], hq.w, a3);
    }
    feats[((size_t)b * 256 + t) * 32 + n] = bo[n] + ((a0 + a1) + (a2 + a3));
  }
}

// ---------------------------------------------------------------------------
// Viterbi: 1 wave per WG, 2 sequences/wave (lanes 0-31 -> b0, 32-63 -> b1).
// ---------------------------------------------------------------------------
__global__ __launch_bounds__(64) void k_viterbi(
    const float* __restrict__ feats, const float* __restrict__ trans,
    int* __restrict__ paths, float* __restrict__ scores)
{
  __shared__ float vbuf[2][32];
  __shared__ float term[2][32];
  __shared__ unsigned char bp[2][256][32];
  __shared__ int tags[2][256];
  const int tid = threadIdx.x;
  const int s = tid >> 5;
  const int n = tid & 31;
  const int b = blockIdx.x * 2 + s;
  float tcol[32];
  #pragma unroll
  for (int p = 0; p < 32; p++) tcol[p] = trans[p * 32 + n];
  float v = (n == 0) ? 0.0f : NEGV;
  const float* fb = feats + (size_t)b * (256 * 32) + n;
  for (int t = 0; t < 256; t++) {
    vbuf[s][n] = v;
    __syncthreads();
    float best = -3.0e38f; int bpi = 0;
    #pragma unroll
    for (int p = 0; p < 32; p++) {
      const float sc = vbuf[s][p] + tcol[p];
      if (sc > best) { best = sc; bpi = p; }   // strict '>' keeps first max (jnp.argmax)
    }
    bp[s][t][n] = (unsigned char)bpi;
    v = best + fb[(size_t)t * 32];
    __syncthreads();
  }
  term[s][n] = v + tcol[0];                    // + trans[0][n]
  __syncthreads();
  if (n == 0) {
    float bs = term[s][0]; int bt = 0;
    for (int p = 1; p < 32; p++) {
      if (term[s][p] > bs) { bs = term[s][p]; bt = p; }
    }
    scores[b] = bs;
    int tg = bt;
    tags[s][255] = tg;
    for (int t = 255; t >= 1; t--) {
      tg = bp[s][t][tg];
      tags[s][t - 1] = tg;
    }
  }
  __syncthreads();
  #pragma unroll
  for (int i = 0; i < 8; i++) {
    const int idx = i * 64 + tid;
    const int ss = idx >> 8;
    const int t = idx & 255;
    paths[(size_t)(blockIdx.x * 2 + ss) * 256 + t] = tags[ss][t];
  }
}

extern "C" void kernel_launch(void* const* d_in, const int* in_sizes, int n_in,
                              void* d_out, int out_size, void* d_ws, size_t ws_size,
                              hipStream_t stream)
{
  (void)in_sizes; (void)n_in; (void)out_size; (void)ws_size;
  const int*   sent  = (const int*)d_in[0];
  const float* embed = (const float*)d_in[1];
  const float* wih_f = (const float*)d_in[2];
  const float* whh_f = (const float*)d_in[3];
  const float* b_f   = (const float*)d_in[4];
  const float* wih_b = (const float*)d_in[5];
  const float* whh_b = (const float*)d_in[6];
  const float* b_b   = (const float*)d_in[7];
  const float* wout  = (const float*)d_in[8];
  const float* bout  = (const float*)d_in[9];
  const float* trans = (const float*)d_in[10];

  char* ws = (char*)d_ws;
  unsigned short* XP = (unsigned short*)(ws);        // 67,108,864 B  [16384][2048] bf16
  __half*   Hg = (__half*)(ws + 67108864);           // 16,777,216 B  [64][256][512] f16
  uint32_t* WQ = (uint32_t*)(ws + 83886080);         //    524,288 B  bf8 Whh
  float*    FT = (float*)(ws + 84410368);            //  2,097,152 B  feats f32

  int*   paths  = (int*)d_out;                       // [64][256] int32 tags
  float* scores = (float*)d_out + 16384;             // [64] f32

  k_quant  <<<dim3(512),  dim3(256), 0, stream>>>(whh_f, whh_b, WQ);
  k_xproj  <<<dim3(2048), dim3(256), 0, stream>>>(sent, embed, wih_f, wih_b, b_f, b_b, XP);
  k_lstm   <<<dim3(128),  dim3(512), 0, stream>>>(XP, WQ, Hg);
  k_feats  <<<dim3(64),   dim3(256), 0, stream>>>(Hg, wout, bout, FT);
  k_viterbi<<<dim3(32),   dim3(64),  0, stream>>>(FT, trans, paths, scores);
}

// Round 3
// 993.440 us; speedup vs baseline: 1.0555x; 1.0555x over previous
//
#include <hip/hip_runtime.h>
#include <hip/hip_fp16.h>
#include <stdint.h>

typedef float  f32x4  __attribute__((ext_vector_type(4)));
typedef short  bf16x8 __attribute__((ext_vector_type(8)));
typedef _Float16 h2v  __attribute__((ext_vector_type(2)));

#define NEGV -10000.0f

__device__ __forceinline__ unsigned short f32_to_bf16(float f){
  union { float f; uint32_t u; } v; v.f = f;
  uint32_t u = v.u;
  u += 0x7fffu + ((u >> 16) & 1u);          // RNE
  return (unsigned short)(u >> 16);
}
__device__ __forceinline__ float bf16_lo(uint32_t u){
  union { uint32_t u; float f; } v; v.u = (u & 0xffffu) << 16; return v.f;
}
__device__ __forceinline__ float bf16_hi(uint32_t u){
  union { uint32_t u; float f; } v; v.u = u & 0xffff0000u; return v.f;
}
// fast gates via exp2 (v_exp_f32); saturate correctly (no inf/inf forms)
#define LOG2E 1.442695041f
__device__ __forceinline__ float fsig(float x){
  return 1.0f / (1.0f + __builtin_exp2f(-LOG2E * x));
}
__device__ __forceinline__ float ftanh_(float x){
  return 1.0f - 2.0f / (__builtin_exp2f(2.0f * LOG2E * x) + 1.0f);
}
// e5m2 ("bf8") = f16 rounded to its top byte
__device__ __forceinline__ uint32_t enc_bf8(float x){
  const unsigned short h = __half_as_ushort(__float2half(x));
  return (uint32_t)((h + 0x80u) >> 8) & 0xffu;
}
__device__ __forceinline__ float fdot2f(uint32_t w, uint32_t h, float acc){
#if __has_builtin(__builtin_amdgcn_fdot2)
  union { uint32_t u; h2v h; } a, b;
  a.u = w; b.u = h;
  return __builtin_amdgcn_fdot2(a.h, b.h, acc, false);
#else
  acc += __half2float(__ushort_as_half((unsigned short)(w & 0xffffu))) *
         __half2float(__ushort_as_half((unsigned short)(h & 0xffffu)));
  acc += __half2float(__ushort_as_half((unsigned short)(w >> 16))) *
         __half2float(__ushort_as_half((unsigned short)(h >> 16)));
  return acc;
#endif
}

// ---------------------------------------------------------------------------
// Quantize Whh_{f,b} [1024,256] f32 -> bf8(e5m2), rows gate-interleaved:
// out row n' = 4*u + g  <-  src row g*256 + u.  Layout: [dir][n'][64 dwords].
// ---------------------------------------------------------------------------
__global__ __launch_bounds__(256) void k_quant(
    const float* __restrict__ whh_f, const float* __restrict__ whh_b,
    uint32_t* __restrict__ wq)
{
  const int id  = blockIdx.x * 256 + threadIdx.x;   // 0..131071
  const int dir = id >> 16;
  const int rem = id & 0xffff;
  const int np  = rem >> 6;
  const int d   = rem & 63;
  const int u = np >> 2, g = np & 3;
  const float* __restrict__ w = dir ? whh_b : whh_f;
  const float4 v = *(const float4*)(w + (size_t)(g * 256 + u) * 256 + d * 4);
  wq[id] = enc_bf8(v.x) | (enc_bf8(v.y) << 8) | (enc_bf8(v.z) << 16) | (enc_bf8(v.w) << 24);
}

// ---------------------------------------------------------------------------
// XP[m][n'] = embed[sent[m]] @ Wih' ^T + b'   (bf16 MFMA, 128x128 tiles)
// ---------------------------------------------------------------------------
__global__ __launch_bounds__(256) void k_xproj(
    const int* __restrict__ sent, const float* __restrict__ embed,
    const float* __restrict__ wih_f, const float* __restrict__ wih_b,
    const float* __restrict__ bias_f, const float* __restrict__ bias_b,
    unsigned short* __restrict__ xp)
{
  __shared__ __align__(16) short At[128 * 32];
  __shared__ __align__(16) short Bt[128 * 32];
  const int bid = blockIdx.x;
  const int tm = bid & 127;
  const int tn = bid >> 7;                  // 0..15
  const int dir = tn >> 3;
  const int nloc0 = (tn & 7) * 128;
  const float* __restrict__ wsrc = dir ? wih_b : wih_f;
  const float* __restrict__ bsrc = dir ? bias_b : bias_f;

  const int tid = threadIdx.x;
  const int wv = tid >> 6;
  const int lane = tid & 63;
  const int lr = lane & 15;
  const int lq = lane >> 4;

  const int r  = tid >> 1;
  const int ch = (tid & 1) * 16;

  const int tok = sent[tm * 128 + r];
  const int nprow = nloc0 + r;
  const float* arow = embed + (size_t)tok * 256 + ch;
  const float* brow = wsrc + (size_t)((nprow & 3) * 256 + (nprow >> 2)) * 256 + ch;
  short* at_dst = At + r * 32 + ch;
  short* bt_dst = Bt + r * 32 + ch;

  f32x4 acc[2][8];
  #pragma unroll
  for (int i = 0; i < 2; i++)
    #pragma unroll
    for (int n = 0; n < 8; n++)
      acc[i][n] = (f32x4){0.f, 0.f, 0.f, 0.f};

  for (int k0 = 0; k0 < 256; k0 += 32) {
    #pragma unroll
    for (int qq = 0; qq < 4; qq++) {
      const float4 va = *(const float4*)(arow + k0 + qq * 4);
      const float4 vb = *(const float4*)(brow + k0 + qq * 4);
      short4 sa, sb;
      sa.x = (short)f32_to_bf16(va.x); sa.y = (short)f32_to_bf16(va.y);
      sa.z = (short)f32_to_bf16(va.z); sa.w = (short)f32_to_bf16(va.w);
      sb.x = (short)f32_to_bf16(vb.x); sb.y = (short)f32_to_bf16(vb.y);
      sb.z = (short)f32_to_bf16(vb.z); sb.w = (short)f32_to_bf16(vb.w);
      *(short4*)(at_dst + qq * 4) = sa;
      *(short4*)(bt_dst + qq * 4) = sb;
    }
    __syncthreads();
    bf16x8 bfr[8];
    #pragma unroll
    for (int n = 0; n < 8; n++)
      bfr[n] = *(const bf16x8*)(Bt + (n * 16 + lr) * 32 + lq * 8);
    #pragma unroll
    for (int i = 0; i < 2; i++) {
      const bf16x8 af = *(const bf16x8*)(At + (wv * 32 + i * 16 + lr) * 32 + lq * 8);
      #pragma unroll
      for (int n = 0; n < 8; n++)
        acc[i][n] = __builtin_amdgcn_mfma_f32_16x16x32_bf16(af, bfr[n], acc[i][n], 0, 0, 0);
    }
    __syncthreads();
  }
  #pragma unroll
  for (int i = 0; i < 2; i++) {
    #pragma unroll
    for (int n = 0; n < 8; n++) {
      const int nloc = nloc0 + n * 16 + lr;
      const float bias = bsrc[(nloc & 3) * 256 + (nloc >> 2)];
      #pragma unroll
      for (int rr = 0; rr < 4; rr++) {
        const int m = tm * 128 + wv * 32 + i * 16 + lq * 4 + rr;
        xp[(size_t)m * 2048 + dir * 1024 + nloc] = f32_to_bf16(acc[i][n][rr] + bias);
      }
    }
  }
}

// ---------------------------------------------------------------------------
// Persistent LSTM v3: round-1 proven structure (16x16x32 bf8_bf8 MFMA,
// zs gate round-trip) + weights forced register-resident via
// __launch_bounds__(512,2) (VGPR cap 256; demand ~212) + xp reg-prefetch.
// ---------------------------------------------------------------------------
__global__ __launch_bounds__(512, 2) void k_lstm(
    const unsigned short* __restrict__ xp, const uint32_t* __restrict__ wq,
    __half* __restrict__ hout)
{
  __shared__ __align__(8) unsigned char hbuf8[256];
  __shared__ __align__(16) float zs[1024];
  const int bid = blockIdx.x;
  const int dir = bid & 1;
  const int b = bid >> 1;
  const int tid = threadIdx.x;
  const int w = tid >> 6;          // wave 0..7
  const int l = tid & 63;
  const int lr = l & 15;           // A row within tile
  const int q = l >> 4;            // quad -> k-offset q*8

  // A fragments: 8 n-tiles x 8 k-tiles x 8 bytes = 128 VGPRs, resident.
  long afr[8][8];
  {
    const uint32_t* wb = wq + dir * 65536;
    #pragma unroll
    for (int ni = 0; ni < 8; ni++) {
      const uint32_t* rp = wb + (w * 128 + ni * 16 + lr) * 64 + q * 2;
      #pragma unroll
      for (int kt = 0; kt < 8; kt++) {
        const uint2 ww = *(const uint2*)(rp + kt * 8);
        afr[ni][kt] = (long)(((unsigned long long)ww.y << 32) | (unsigned long long)ww.x);
      }
    }
  }
  float c = 0.0f;
  if (tid < 256) hbuf8[tid] = 0;
  const unsigned short* xpb = xp + (size_t)b * (256 * 2048) + dir * 1024 + w * 128 + q * 4;
  __half* hb = hout + (size_t)b * (256 * 512) + dir * 256 + tid;   // tid<256 uses this

  // prefetch xp for first step
  uint2 xpr[8];
  {
    const int t0 = dir ? 255 : 0;
    const unsigned short* xr = xpb + (size_t)t0 * 2048;
    #pragma unroll
    for (int ni = 0; ni < 8; ni++)
      xpr[ni] = *(const uint2*)(xr + ni * 16);
  }
  __syncthreads();

  for (int s = 0; s < 256; s++) {
    const int t = dir ? (255 - s) : s;
    // acc init from prefetched xp (bf16 -> f32)
    f32x4 acc[8];
    #pragma unroll
    for (int ni = 0; ni < 8; ni++) {
      acc[ni].x = bf16_lo(xpr[ni].x);
      acc[ni].y = bf16_hi(xpr[ni].x);
      acc[ni].z = bf16_lo(xpr[ni].y);
      acc[ni].w = bf16_hi(xpr[ni].y);
    }
    // issue next step's xp prefetch (latency hidden under the MFMAs)
    {
      const int sn = (s < 255) ? (s + 1) : 255;
      const int tn = dir ? (255 - sn) : sn;
      const unsigned short* xr = xpb + (size_t)tn * 2048;
      #pragma unroll
      for (int ni = 0; ni < 8; ni++)
        xpr[ni] = *(const uint2*)(xr + ni * 16);
    }
    // B fragments from h bytes (broadcast across lr)
    long bfr[8];
    #pragma unroll
    for (int kt = 0; kt < 8; kt++)
      bfr[kt] = *(const long*)(hbuf8 + kt * 32 + q * 8);
    #pragma unroll
    for (int kt = 0; kt < 8; kt++)
      #pragma unroll
      for (int ni = 0; ni < 8; ni++)
        acc[ni] = __builtin_amdgcn_mfma_f32_16x16x32_bf8_bf8(afr[ni][kt], bfr[kt], acc[ni], 0, 0, 0);
    // all 16 lr lanes hold identical z; lr==0 publishes
    if (lr == 0) {
      #pragma unroll
      for (int ni = 0; ni < 8; ni++)
        *(f32x4*)(zs + (w * 32 + ni * 4 + q) * 4) = acc[ni];
    }
    __syncthreads();
    if (tid < 256) {
      const float4 z4 = *(const float4*)(zs + tid * 4);
      const float ig = fsig(z4.x);
      const float fg = fsig(z4.y);
      const float gg = ftanh_(z4.z);
      const float og = fsig(z4.w);
      c = fg * c + ig * gg;
      const float h = og * ftanh_(c);
      hb[(size_t)t * 512] = __float2half(h);
      const unsigned short h16 = __half_as_ushort(__float2half(h));
      hbuf8[tid] = (unsigned char)((h16 + 0x80u) >> 8);
    }
    __syncthreads();
  }
}

// ---------------------------------------------------------------------------
// feats[b][t][n] = H[b][t][:512] . Wout[n] + bout[n]   (f16 dot2, Wout in LDS)
// ---------------------------------------------------------------------------
__global__ __launch_bounds__(256) void k_feats(
    const __half* __restrict__ hg, const float* __restrict__ wout,
    const float* __restrict__ bout, float* __restrict__ feats)
{
  __shared__ uint32_t W2[32 * 257];
  __shared__ float bo[32];
  const int b = blockIdx.x;
  const int tid = threadIdx.x;
  #pragma unroll
  for (int i = 0; i < 32; i++) {
    const float2 v = *(const float2*)(wout + (size_t)i * 512 + tid * 2);
    const uint32_t lo = (uint32_t)__half_as_ushort(__float2half(v.x));
    const uint32_t hi = (uint32_t)__half_as_ushort(__float2half(v.y));
    W2[i * 257 + tid] = lo | (hi << 16);
  }
  if (tid < 32) bo[tid] = bout[tid];
  __syncthreads();
  const int n = tid & 31;
  const int tg = tid >> 5;
  const uint32_t* hrow0 = (const uint32_t*)(hg + (size_t)b * (256 * 512));
  for (int tt = 0; tt < 32; tt++) {
    const int t = tg * 32 + tt;
    const uint4* hr = (const uint4*)(hrow0 + t * 256);
    float a0 = 0.f, a1 = 0.f, a2 = 0.f, a3 = 0.f;
    #pragma unroll
    for (int qd = 0; qd < 64; qd++) {
      const uint4 hq = hr[qd];
      a0 = fdot2f(W2[n * 257 + qd * 4 + 0], hq.x, a0);
      a1 = fdot2f(W2[n * 257 + qd * 4 + 1], hq.y, a1);
      a2 = fdot2f(W2[n * 257 + qd * 4 + 2], hq.z, a2);
      a3 = fdot2f(W2[n * 257 + qd * 4 + 3], hq.w, a3);
    }
    feats[((size_t)b * 256 + t) * 32 + n] = bo[n] + ((a0 + a1) + (a2 + a3));
  }
}

// ---------------------------------------------------------------------------
// Viterbi: 1 wave per WG, 2 sequences/wave (lanes 0-31 -> b0, 32-63 -> b1).
// ---------------------------------------------------------------------------
__global__ __launch_bounds__(64) void k_viterbi(
    const float* __restrict__ feats, const float* __restrict__ trans,
    int* __restrict__ paths, float* __restrict__ scores)
{
  __shared__ float vbuf[2][32];
  __shared__ float term[2][32];
  __shared__ unsigned char bp[2][256][32];
  __shared__ int tags[2][256];
  const int tid = threadIdx.x;
  const int s = tid >> 5;
  const int n = tid & 31;
  const int b = blockIdx.x * 2 + s;
  float tcol[32];
  #pragma unroll
  for (int p = 0; p < 32; p++) tcol[p] = trans[p * 32 + n];
  float v = (n == 0) ? 0.0f : NEGV;
  const float* fb = feats + (size_t)b * (256 * 32) + n;
  for (int t = 0; t < 256; t++) {
    vbuf[s][n] = v;
    __syncthreads();
    float best = -3.0e38f; int bpi = 0;
    #pragma unroll
    for (int p = 0; p < 32; p++) {
      const float sc = vbuf[s][p] + tcol[p];
      if (sc > best) { best = sc; bpi = p; }   // strict '>' keeps first max (jnp.argmax)
    }
    bp[s][t][n] = (unsigned char)bpi;
    v = best + fb[(size_t)t * 32];
    __syncthreads();
  }
  term[s][n] = v + tcol[0];                    // + trans[0][n]
  __syncthreads();
  if (n == 0) {
    float bs = term[s][0]; int bt = 0;
    for (int p = 1; p < 32; p++) {
      if (term[s][p] > bs) { bs = term[s][p]; bt = p; }
    }
    scores[b] = bs;
    int tg = bt;
    tags[s][255] = tg;
    for (int t = 255; t >= 1; t--) {
      tg = bp[s][t][tg];
      tags[s][t - 1] = tg;
    }
  }
  __syncthreads();
  #pragma unroll
  for (int i = 0; i < 8; i++) {
    const int idx = i * 64 + tid;
    const int ss = idx >> 8;
    const int t = idx & 255;
    paths[(size_t)(blockIdx.x * 2 + ss) * 256 + t] = tags[ss][t];
  }
}

extern "C" void kernel_launch(void* const* d_in, const int* in_sizes, int n_in,
                              void* d_out, int out_size, void* d_ws, size_t ws_size,
                              hipStream_t stream)
{
  (void)in_sizes; (void)n_in; (void)out_size; (void)ws_size;
  const int*   sent  = (const int*)d_in[0];
  const float* embed = (const float*)d_in[1];
  const float* wih_f = (const float*)d_in[2];
  const float* whh_f = (const float*)d_in[3];
  const float* b_f   = (const float*)d_in[4];
  const float* wih_b = (const float*)d_in[5];
  const float* whh_b = (const float*)d_in[6];
  const float* b_b   = (const float*)d_in[7];
  const float* wout  = (const float*)d_in[8];
  const float* bout  = (const float*)d_in[9];
  const float* trans = (const float*)d_in[10];

  char* ws = (char*)d_ws;
  unsigned short* XP = (unsigned short*)(ws);        // 67,108,864 B  [16384][2048] bf16
  __half*   Hg = (__half*)(ws + 67108864);           // 16,777,216 B  [64][256][512] f16
  uint32_t* WQ = (uint32_t*)(ws + 83886080);         //    524,288 B  bf8 Whh
  float*    FT = (float*)(ws + 84410368);            //  2,097,152 B  feats f32

  int*   paths  = (int*)d_out;                       // [64][256] int32 tags
  float* scores = (float*)d_out + 16384;             // [64] f32

  k_quant  <<<dim3(512),  dim3(256), 0, stream>>>(whh_f, whh_b, WQ);
  k_xproj  <<<dim3(2048), dim3(256), 0, stream>>>(sent, embed, wih_f, wih_b, b_f, b_b, XP);
  k_lstm   <<<dim3(128),  dim3(512), 0, stream>>>(XP, WQ, Hg);
  k_feats  <<<dim3(64),   dim3(256), 0, stream>>>(Hg, wout, bout, FT);
  k_viterbi<<<dim3(32),   dim3(64),  0, stream>>>(FT, trans, paths, scores);
}

// Round 4
// 777.936 us; speedup vs baseline: 1.3478x; 1.2770x over previous
//
#include <hip/hip_runtime.h>
#include <hip/hip_fp16.h>
#include <stdint.h>

typedef float  f32x4  __attribute__((ext_vector_type(4)));
typedef int    i32x4  __attribute__((ext_vector_type(4)));
typedef short  bf16x8 __attribute__((ext_vector_type(8)));
typedef _Float16 h2v  __attribute__((ext_vector_type(2)));

#define NEGV -10000.0f
#define LOG2E 1.442695041f

__device__ __forceinline__ unsigned short f32_to_bf16(float f){
  union { float f; uint32_t u; } v; v.f = f;
  uint32_t u = v.u;
  u += 0x7fffu + ((u >> 16) & 1u);          // RNE
  return (unsigned short)(u >> 16);
}
__device__ __forceinline__ float bf16_lo(uint32_t u){
  union { uint32_t u; float f; } v; v.u = (u & 0xffffu) << 16; return v.f;
}
__device__ __forceinline__ float bf16_hi(uint32_t u){
  union { uint32_t u; float f; } v; v.u = u & 0xffff0000u; return v.f;
}
// fast gates: exp2 + rcp (both single hw ops); saturate correctly, no NaN
__device__ __forceinline__ float fsig(float x){
  return __builtin_amdgcn_rcpf(1.0f + __builtin_exp2f(-LOG2E * x));
}
__device__ __forceinline__ float ftanh_(float x){
  return 1.0f - 2.0f * __builtin_amdgcn_rcpf(1.0f + __builtin_exp2f(2.0f * LOG2E * x));
}
// i8 weight quant, scale 512 (|w| <= 0.248 covered; clamp otherwise)
__device__ __forceinline__ uint32_t enc_i8(float x){
  int v = (int)rintf(x * 512.0f);
  v = v > 127 ? 127 : (v < -127 ? -127 : v);
  return (uint32_t)(v & 0xff);
}
__device__ __forceinline__ float fdot2f(uint32_t w, uint32_t h, float acc){
#if __has_builtin(__builtin_amdgcn_fdot2)
  union { uint32_t u; h2v h; } a, b;
  a.u = w; b.u = h;
  return __builtin_amdgcn_fdot2(a.h, b.h, acc, false);
#else
  acc += __half2float(__ushort_as_half((unsigned short)(w & 0xffffu))) *
         __half2float(__ushort_as_half((unsigned short)(h & 0xffffu)));
  acc += __half2float(__ushort_as_half((unsigned short)(w >> 16))) *
         __half2float(__ushort_as_half((unsigned short)(h >> 16)));
  return acc;
#endif
}
// raw workgroup barrier: wait LDS only, do NOT drain vmcnt (keeps xp
// prefetch + h stores in flight across the barrier)
__device__ __forceinline__ void wg_barrier_lds(){
  __builtin_amdgcn_s_waitcnt(0xC07F);   // lgkmcnt(0), vmcnt/expcnt untouched
  asm volatile("" ::: "memory");
  __builtin_amdgcn_s_barrier();
  asm volatile("" ::: "memory");
}

// ---------------------------------------------------------------------------
// Quantize Whh_{f,b} [1024,256] f32 -> i8 (x512), rows gate-interleaved:
// out row n' = 4*u + g  <-  src row g*256 + u.  Layout: [dir][n'][64 dwords].
// ---------------------------------------------------------------------------
__global__ __launch_bounds__(256) void k_quant(
    const float* __restrict__ whh_f, const float* __restrict__ whh_b,
    uint32_t* __restrict__ wq)
{
  const int id  = blockIdx.x * 256 + threadIdx.x;   // 0..131071
  const int dir = id >> 16;
  const int rem = id & 0xffff;
  const int np  = rem >> 6;
  const int d   = rem & 63;
  const int u = np >> 2, g = np & 3;
  const float* __restrict__ w = dir ? whh_b : whh_f;
  const float4 v = *(const float4*)(w + (size_t)(g * 256 + u) * 256 + d * 4);
  wq[id] = enc_i8(v.x) | (enc_i8(v.y) << 8) | (enc_i8(v.z) << 16) | (enc_i8(v.w) << 24);
}

// ---------------------------------------------------------------------------
// XP[m][n'] = embed[sent[m]] @ Wih' ^T + b'   (bf16 MFMA, 128x128 tiles)
// ---------------------------------------------------------------------------
__global__ __launch_bounds__(256) void k_xproj(
    const int* __restrict__ sent, const float* __restrict__ embed,
    const float* __restrict__ wih_f, const float* __restrict__ wih_b,
    const float* __restrict__ bias_f, const float* __restrict__ bias_b,
    unsigned short* __restrict__ xp)
{
  __shared__ __align__(16) short At[128 * 32];
  __shared__ __align__(16) short Bt[128 * 32];
  const int bid = blockIdx.x;
  const int tm = bid & 127;
  const int tn = bid >> 7;                  // 0..15
  const int dir = tn >> 3;
  const int nloc0 = (tn & 7) * 128;
  const float* __restrict__ wsrc = dir ? wih_b : wih_f;
  const float* __restrict__ bsrc = dir ? bias_b : bias_f;

  const int tid = threadIdx.x;
  const int wv = tid >> 6;
  const int lane = tid & 63;
  const int lr = lane & 15;
  const int lq = lane >> 4;

  const int r  = tid >> 1;
  const int ch = (tid & 1) * 16;

  const int tok = sent[tm * 128 + r];
  const int nprow = nloc0 + r;
  const float* arow = embed + (size_t)tok * 256 + ch;
  const float* brow = wsrc + (size_t)((nprow & 3) * 256 + (nprow >> 2)) * 256 + ch;
  short* at_dst = At + r * 32 + ch;
  short* bt_dst = Bt + r * 32 + ch;

  f32x4 acc[2][8];
  #pragma unroll
  for (int i = 0; i < 2; i++)
    #pragma unroll
    for (int n = 0; n < 8; n++)
      acc[i][n] = (f32x4){0.f, 0.f, 0.f, 0.f};

  for (int k0 = 0; k0 < 256; k0 += 32) {
    #pragma unroll
    for (int qq = 0; qq < 4; qq++) {
      const float4 va = *(const float4*)(arow + k0 + qq * 4);
      const float4 vb = *(const float4*)(brow + k0 + qq * 4);
      short4 sa, sb;
      sa.x = (short)f32_to_bf16(va.x); sa.y = (short)f32_to_bf16(va.y);
      sa.z = (short)f32_to_bf16(va.z); sa.w = (short)f32_to_bf16(va.w);
      sb.x = (short)f32_to_bf16(vb.x); sb.y = (short)f32_to_bf16(vb.y);
      sb.z = (short)f32_to_bf16(vb.z); sb.w = (short)f32_to_bf16(vb.w);
      *(short4*)(at_dst + qq * 4) = sa;
      *(short4*)(bt_dst + qq * 4) = sb;
    }
    __syncthreads();
    bf16x8 bfr[8];
    #pragma unroll
    for (int n = 0; n < 8; n++)
      bfr[n] = *(const bf16x8*)(Bt + (n * 16 + lr) * 32 + lq * 8);
    #pragma unroll
    for (int i = 0; i < 2; i++) {
      const bf16x8 af = *(const bf16x8*)(At + (wv * 32 + i * 16 + lr) * 32 + lq * 8);
      #pragma unroll
      for (int n = 0; n < 8; n++)
        acc[i][n] = __builtin_amdgcn_mfma_f32_16x16x32_bf16(af, bfr[n], acc[i][n], 0, 0, 0);
    }
    __syncthreads();
  }
  #pragma unroll
  for (int i = 0; i < 2; i++) {
    #pragma unroll
    for (int n = 0; n < 8; n++) {
      const int nloc = nloc0 + n * 16 + lr;
      const float bias = bsrc[(nloc & 3) * 256 + (nloc >> 2)];
      #pragma unroll
      for (int rr = 0; rr < 4; rr++) {
        const int m = tm * 128 + wv * 32 + i * 16 + lq * 4 + rr;
        xp[(size_t)m * 2048 + dir * 1024 + nloc] = f32_to_bf16(acc[i][n][rr] + bias);
      }
    }
  }
}

// ---------------------------------------------------------------------------
// Persistent LSTM v4: 1 WG (512 thr, 8 waves) per (b,dir).
//  - Whh i8 (x512) in registers as 16x16x64 i8-MFMA A-fragments, residency
//    FORCED via opaque asm (compiler cannot rematerialize).
//  - h i8 (x128) in LDS, double-buffered; ONE raw barrier per step
//    (lgkmcnt only -- vmcnt stays outstanding across the barrier).
//  - Gates computed in-lane (cndmask-select the owned ni), no zs round-trip.
//  - xp prefetched 2 steps ahead in two register sets.
// ---------------------------------------------------------------------------
__global__ __launch_bounds__(512, 2) void k_lstm(
    const unsigned short* __restrict__ xp, const uint32_t* __restrict__ wq,
    __half* __restrict__ hout)
{
  __shared__ __align__(16) unsigned char hbuf[2][256];
  const int bid = blockIdx.x;
  const int dir = bid & 1;
  const int b = bid >> 1;
  const int tid = threadIdx.x;
  const int w = tid >> 6;          // wave 0..7
  const int l = tid & 63;
  const int lr = l & 15;           // A row within 16-row tile
  const int q = l >> 4;            // quad -> k-offset q*16 within 64-k tile
  const int nio = lr & 7;          // owned ni (lanes lr and lr+8 mirror)
  const int u = w * 32 + nio * 4 + q;   // owned LSTM unit

  // A fragments: 8 ni x 4 kt x 16B = 128 VGPRs, forced resident
  i32x4 afr[8][4];
  {
    const unsigned char* wb = (const unsigned char*)wq + (size_t)dir * 262144;
    #pragma unroll
    for (int ni = 0; ni < 8; ni++) {
      const unsigned char* rp = wb + (size_t)(w * 128 + ni * 16 + lr) * 256 + q * 16;
      #pragma unroll
      for (int kt = 0; kt < 4; kt++) {
        afr[ni][kt] = *(const i32x4*)(rp + kt * 64);
        asm volatile("" : "+v"(afr[ni][kt].x), "+v"(afr[ni][kt].y),
                          "+v"(afr[ni][kt].z), "+v"(afr[ni][kt].w));
      }
    }
  }
  if (tid < 64) ((uint32_t*)hbuf[0])[tid] = 0;   // h_{-1} = 0
  float c = 0.0f;
  const unsigned short* xpb = xp + (size_t)b * (256 * 2048) + dir * 1024 + w * 128 + q * 4;
  __half* hb = hout + (size_t)b * (256 * 512) + dir * 256 + u;   // lr<8 lanes

  // prefetch xp for steps 0 and 1
  uint2 xa[8], xb[8];
  {
    const int t0 = dir ? 255 : 0;
    const int t1 = dir ? 254 : 1;
    #pragma unroll
    for (int ni = 0; ni < 8; ni++) {
      xa[ni] = *(const uint2*)(xpb + (size_t)t0 * 2048 + ni * 16);
      xb[ni] = *(const uint2*)(xpb + (size_t)t1 * 2048 + ni * 16);
    }
  }
  __syncthreads();   // full fence once: hbuf[0] zero visible

#define LSTM_STEP(SS, SRD, SWR, XC)                                          \
  {                                                                          \
    const int t_ = dir ? (255 - (SS)) : (SS);                                \
    i32x4 bfr[4];                                                            \
    _Pragma("unroll")                                                        \
    for (int kt = 0; kt < 4; kt++)                                           \
      bfr[kt] = *(const i32x4*)(&hbuf[SRD][kt * 64 + q * 16]);               \
    i32x4 acc[8];                                                            \
    _Pragma("unroll")                                                        \
    for (int ni = 0; ni < 8; ni++) acc[ni] = (i32x4){0, 0, 0, 0};            \
    _Pragma("unroll")                                                        \
    for (int kt = 0; kt < 4; kt++)                                           \
      _Pragma("unroll")                                                      \
      for (int ni = 0; ni < 8; ni++)                                         \
        acc[ni] = __builtin_amdgcn_mfma_i32_16x16x64_i8(                     \
            afr[ni][kt], bfr[kt], acc[ni], 0, 0, 0);                         \
    i32x4 zi = acc[0];                                                       \
    uint32_t x0 = XC[0].x, x1 = XC[0].y;                                     \
    _Pragma("unroll")                                                        \
    for (int ni = 1; ni < 8; ni++) {                                         \
      const bool own = (nio == ni);                                          \
      zi.x = own ? acc[ni].x : zi.x;                                         \
      zi.y = own ? acc[ni].y : zi.y;                                         \
      zi.z = own ? acc[ni].z : zi.z;                                         \
      zi.w = own ? acc[ni].w : zi.w;                                         \
      x0 = own ? XC[ni].x : x0;                                              \
      x1 = own ? XC[ni].y : x1;                                              \
    }                                                                        \
    const float SINV = 1.0f / 65536.0f;                                      \
    const float z_i = (float)zi.x * SINV + bf16_lo(x0);                      \
    const float z_f = (float)zi.y * SINV + bf16_hi(x0);                      \
    const float z_g = (float)zi.z * SINV + bf16_lo(x1);                      \
    const float z_o = (float)zi.w * SINV + bf16_hi(x1);                      \
    const float ig = fsig(z_i), fg = fsig(z_f);                              \
    const float gg = ftanh_(z_g), og = fsig(z_o);                            \
    c = fg * c + ig * gg;                                                    \
    const float h_ = og * ftanh_(c);                                         \
    {  /* prefetch xp for step SS+2 (overwrites XC after use) */             \
      int spf = (SS) + 2; spf = spf > 255 ? 255 : spf;                       \
      const int tpf = dir ? (255 - spf) : spf;                               \
      const unsigned short* xr = xpb + (size_t)tpf * 2048;                   \
      _Pragma("unroll")                                                      \
      for (int ni = 0; ni < 8; ni++)                                         \
        XC[ni] = *(const uint2*)(xr + ni * 16);                              \
    }                                                                        \
    if (lr < 8) {                                                            \
      hb[(size_t)t_ * 512] = __float2half(h_);                               \
      int hq = (int)rintf(h_ * 128.0f);                                      \
      hq = hq > 127 ? 127 : (hq < -127 ? -127 : hq);                         \
      hbuf[SWR][u] = (unsigned char)(hq & 0xff);                             \
    }                                                                        \
    wg_barrier_lds();                                                        \
  }

  for (int s = 0; s < 256; s += 2) {
    LSTM_STEP(s,     0, 1, xa)
    LSTM_STEP(s + 1, 1, 0, xb)
  }
#undef LSTM_STEP
}

// ---------------------------------------------------------------------------
// feats[b][t][n] = H[b][t][:512] . Wout[n] + bout[n]   (f16 dot2, Wout in LDS)
// ---------------------------------------------------------------------------
__global__ __launch_bounds__(256) void k_feats(
    const __half* __restrict__ hg, const float* __restrict__ wout,
    const float* __restrict__ bout, float* __restrict__ feats)
{
  __shared__ uint32_t W2[32 * 257];
  __shared__ float bo[32];
  const int b = blockIdx.x;
  const int tid = threadIdx.x;
  #pragma unroll
  for (int i = 0; i < 32; i++) {
    const float2 v = *(const float2*)(wout + (size_t)i * 512 + tid * 2);
    const uint32_t lo = (uint32_t)__half_as_ushort(__float2half(v.x));
    const uint32_t hi = (uint32_t)__half_as_ushort(__float2half(v.y));
    W2[i * 257 + tid] = lo | (hi << 16);
  }
  if (tid < 32) bo[tid] = bout[tid];
  __syncthreads();
  const int n = tid & 31;
  const int tg = tid >> 5;
  const uint32_t* hrow0 = (const uint32_t*)(hg + (size_t)b * (256 * 512));
  for (int tt = 0; tt < 32; tt++) {
    const int t = tg * 32 + tt;
    const uint4* hr = (const uint4*)(hrow0 + t * 256);
    float a0 = 0.f, a1 = 0.f, a2 = 0.f, a3 = 0.f;
    #pragma unroll
    for (int qd = 0; qd < 64; qd++) {
      const uint4 hq = hr[qd];
      a0 = fdot2f(W2[n * 257 + qd * 4 + 0], hq.x, a0);
      a1 = fdot2f(W2[n * 257 + qd * 4 + 1], hq.y, a1);
      a2 = fdot2f(W2[n * 257 + qd * 4 + 2], hq.z, a2);
      a3 = fdot2f(W2[n * 257 + qd * 4 + 3], hq.w, a3);
    }
    feats[((size_t)b * 256 + t) * 32 + n] = bo[n] + ((a0 + a1) + (a2 + a3));
  }
}

// ---------------------------------------------------------------------------
// Viterbi: 1 wave per WG, 2 sequences/wave (lanes 0-31 -> b0, 32-63 -> b1).
// ---------------------------------------------------------------------------
__global__ __launch_bounds__(64) void k_viterbi(
    const float* __restrict__ feats, const float* __restrict__ trans,
    int* __restrict__ paths, float* __restrict__ scores)
{
  __shared__ float vbuf[2][32];
  __shared__ float term[2][32];
  __shared__ unsigned char bp[2][256][32];
  __shared__ int tags[2][256];
  const int tid = threadIdx.x;
  const int s = tid >> 5;
  const int n = tid & 31;
  const int b = blockIdx.x * 2 + s;
  float tcol[32];
  #pragma unroll
  for (int p = 0; p < 32; p++) tcol[p] = trans[p * 32 + n];
  float v = (n == 0) ? 0.0f : NEGV;
  const float* fb = feats + (size_t)b * (256 * 32) + n;
  for (int t = 0; t < 256; t++) {
    vbuf[s][n] = v;
    __syncthreads();
    float best = -3.0e38f; int bpi = 0;
    #pragma unroll
    for (int p = 0; p < 32; p++) {
      const float sc = vbuf[s][p] + tcol[p];
      if (sc > best) { best = sc; bpi = p; }   // strict '>' keeps first max (jnp.argmax)
    }
    bp[s][t][n] = (unsigned char)bpi;
    v = best + fb[(size_t)t * 32];
    __syncthreads();
  }
  term[s][n] = v + tcol[0];                    // + trans[0][n]
  __syncthreads();
  if (n == 0) {
    float bs = term[s][0]; int bt = 0;
    for (int p = 1; p < 32; p++) {
      if (term[s][p] > bs) { bs = term[s][p]; bt = p; }
    }
    scores[b] = bs;
    int tg = bt;
    tags[s][255] = tg;
    for (int t = 255; t >= 1; t--) {
      tg = bp[s][t][tg];
      tags[s][t - 1] = tg;
    }
  }
  __syncthreads();
  #pragma unroll
  for (int i = 0; i < 8; i++) {
    const int idx = i * 64 + tid;
    const int ss = idx >> 8;
    const int t = idx & 255;
    paths[(size_t)(blockIdx.x * 2 + ss) * 256 + t] = tags[ss][t];
  }
}

extern "C" void kernel_launch(void* const* d_in, const int* in_sizes, int n_in,
                              void* d_out, int out_size, void* d_ws, size_t ws_size,
                              hipStream_t stream)
{
  (void)in_sizes; (void)n_in; (void)out_size; (void)ws_size;
  const int*   sent  = (const int*)d_in[0];
  const float* embed = (const float*)d_in[1];
  const float* wih_f = (const float*)d_in[2];
  const float* whh_f = (const float*)d_in[3];
  const float* b_f   = (const float*)d_in[4];
  const float* wih_b = (const float*)d_in[5];
  const float* whh_b = (const float*)d_in[6];
  const float* b_b   = (const float*)d_in[7];
  const float* wout  = (const float*)d_in[8];
  const float* bout  = (const float*)d_in[9];
  const float* trans = (const float*)d_in[10];

  char* ws = (char*)d_ws;
  unsigned short* XP = (unsigned short*)(ws);        // 67,108,864 B  [16384][2048] bf16
  __half*   Hg = (__half*)(ws + 67108864);           // 16,777,216 B  [64][256][512] f16
  uint32_t* WQ = (uint32_t*)(ws + 83886080);         //    524,288 B  i8 Whh
  float*    FT = (float*)(ws + 84410368);            //  2,097,152 B  feats f32

  int*   paths  = (int*)d_out;                       // [64][256] int32 tags
  float* scores = (float*)d_out + 16384;             // [64] f32

  k_quant  <<<dim3(512),  dim3(256), 0, stream>>>(whh_f, whh_b, WQ);
  k_xproj  <<<dim3(2048), dim3(256), 0, stream>>>(sent, embed, wih_f, wih_b, b_f, b_b, XP);
  k_lstm   <<<dim3(128),  dim3(512), 0, stream>>>(XP, WQ, Hg);
  k_feats  <<<dim3(64),   dim3(256), 0, stream>>>(Hg, wout, bout, FT);
  k_viterbi<<<dim3(32),   dim3(64),  0, stream>>>(FT, trans, paths, scores);
}